// Round 12
// baseline (209.168 us; speedup 1.0000x reference)
//
#include <hip/hip_runtime.h>
#include <math.h>

#define BB   256   // batch
#define OBS  256
#define HH   1024
#define AA   18

// clang-native packed f16: + -> v_pk_add_f16, elementwise_max -> v_pk_max_f16
typedef _Float16 h2 __attribute__((ext_vector_type(2)));

static __device__ __forceinline__ h2 u2h(unsigned int u) {
  return __builtin_bit_cast(h2, u);
}
static __device__ __forceinline__ unsigned int h2u(h2 v) {
  return __builtin_bit_cast(unsigned int, v);
}

// ---------------------------------------------------------------------------
// fc_in (R10 structure): h1pk[o/2][b] = pack_f16( x@W_in^T + b_in )
// grid (H/16, B/64), block 1024 = 8 k-splits x 2 o-octets. lane = b.
// x and W_in tiles staged in LDS.
// ---------------------------------------------------------------------------
__global__ __launch_bounds__(1024) void fc_in_kernel(
    const float* __restrict__ x, const float* __restrict__ Wi,
    const float* __restrict__ bi, unsigned int* __restrict__ h1pk) {
  __shared__ float xs[64][OBS + 1];    // 65.8 KB
  __shared__ float ws_[16][260];       // 16.6 KB
  __shared__ float red[8][16][64];     // 32 KB
  const int t    = threadIdx.x;
  const int lane = t & 63;
  const int wv   = __builtin_amdgcn_readfirstlane(t >> 6);
  const int oq   = wv & 1;
  const int s    = wv >> 1;        // k-split: 32 k each
  const int og   = blockIdx.x;
  const int bg   = blockIdx.y;
  const int k0   = s * 32;

  {
    const int row = t >> 4;          // 0..63
    const int c4  = t & 15;          // 0..15
    const float4* src = (const float4*)(x + (size_t)(bg * 64 + row) * OBS);
#pragma unroll
    for (int k = 0; k < 4; ++k) {
      const float4 v = src[c4 + 16 * k];
      const int col = (c4 + 16 * k) * 4;
      xs[row][col]     = v.x;
      xs[row][col + 1] = v.y;
      xs[row][col + 2] = v.z;
      xs[row][col + 3] = v.w;
    }
  }
  {
    const int row = wv;              // 0..15
    const int c   = lane;            // 0..63
    const float4 v =
        ((const float4*)(Wi + (size_t)(og * 16 + row) * OBS))[c];
    const int col = c * 4;
    ws_[row][col]     = v.x;
    ws_[row][col + 1] = v.y;
    ws_[row][col + 2] = v.z;
    ws_[row][col + 3] = v.w;
  }
  __syncthreads();

  const int ob = oq * 8;
  float acc[8] = {0, 0, 0, 0, 0, 0, 0, 0};

#pragma unroll
  for (int k = 0; k < 32; k += 4) {
    const int kk = k0 + k;
    const float x0 = xs[lane][kk];
    const float x1 = xs[lane][kk + 1];
    const float x2 = xs[lane][kk + 2];
    const float x3 = xs[lane][kk + 3];
#pragma unroll
    for (int j = 0; j < 8; ++j) {
      const float4 w4 = *(const float4*)&ws_[ob + j][kk];
      acc[j] = fmaf(x0, w4.x, acc[j]);
      acc[j] = fmaf(x1, w4.y, acc[j]);
      acc[j] = fmaf(x2, w4.z, acc[j]);
      acc[j] = fmaf(x3, w4.w, acc[j]);
    }
  }

#pragma unroll
  for (int j = 0; j < 8; ++j) red[s][ob + j][lane] = acc[j];
  __syncthreads();

  if (t < 512) {
    const int op = t >> 6;
    const int bl = t & 63;
    float s0 = 0.f, s1 = 0.f;
#pragma unroll
    for (int ks = 0; ks < 8; ++ks) {
      s0 += red[ks][2 * op][bl];
      s1 += red[ks][2 * op + 1][bl];
    }
    s0 += bi[og * 16 + 2 * op];
    s1 += bi[og * 16 + 2 * op + 1];
    h2 p = {(_Float16)s0, (_Float16)s1};
    h1pk[(size_t)(og * 8 + op) * BB + bg * 64 + bl] = h2u(p);
  }
}

// ---------------------------------------------------------------------------
// max-plus (R8 config, unchanged): out[o][b] = max_i( W[o][i] + h[i][b] )
// grid (H/8, B/64), block 1024 = 16 i-splits. Thread tile 2o x 4b.
// ---------------------------------------------------------------------------
__global__ __launch_bounds__(1024) void mmplus_max_kernel(
    const unsigned int* __restrict__ hpk,   // [H/2][B]
    const float* __restrict__ Wf,           // [H][H] f32
    unsigned int* __restrict__ opk) {       // [H/2][B]
  constexpr int PITCH = 514;
  __shared__ __align__(16) unsigned int lds[8 * PITCH];
  const int t    = threadIdx.x;
  const int lane = t & 63;
  const int og2  = lane >> 4;
  const int bq   = lane & 15;
  const int s    = __builtin_amdgcn_readfirstlane(t >> 6);
  const int og   = blockIdx.x;
  const int bg   = blockIdx.y;

  {
    const int o_l = t >> 7;
    const int c   = t & 127;
    const float4* src = (const float4*)(Wf + (size_t)(og * 8 + o_l) * HH);
    unsigned int* dst = &lds[o_l * PITCH];
#pragma unroll
    for (int k = 0; k < 2; ++k) {
      const float4 v = src[c + 128 * k];
      h2 p0 = {(_Float16)v.x, (_Float16)v.y};
      h2 p1 = {(_Float16)v.z, (_Float16)v.w};
      *(uint2*)&dst[(c + 128 * k) * 2] = make_uint2(h2u(p0), h2u(p1));
    }
  }
  __syncthreads();

  const unsigned int* __restrict__ hp =
      hpk + (size_t)(s * 32) * BB + bg * 64 + bq * 4;
  const _Float16 INIT = (_Float16)(-65504.f);
  h2 acc[2][4];
#pragma unroll
  for (int j = 0; j < 2; ++j)
#pragma unroll
    for (int bb = 0; bb < 4; ++bb) acc[j][bb] = (h2){INIT, INIT};

#pragma unroll 4
  for (int it = 0; it < 16; ++it) {
    const int p = it * 2;
    const uint4 h0 = *(const uint4*)(hp + (size_t)p * BB);
    const uint4 h1 = *(const uint4*)(hp + (size_t)(p + 1) * BB);
    const h2 h0v[4] = {u2h(h0.x), u2h(h0.y), u2h(h0.z), u2h(h0.w)};
    const h2 h1v[4] = {u2h(h1.x), u2h(h1.y), u2h(h1.z), u2h(h1.w)};
#pragma unroll
    for (int j = 0; j < 2; ++j) {
      const uint2 wj = *(const uint2*)&lds[(og2 * 2 + j) * PITCH + s * 32 + p];
      const h2 wa = u2h(wj.x);
      const h2 wb = u2h(wj.y);
#pragma unroll
      for (int bb = 0; bb < 4; ++bb) {
        acc[j][bb] = __builtin_elementwise_max(acc[j][bb], wa + h0v[bb]);
        acc[j][bb] = __builtin_elementwise_max(acc[j][bb], wb + h1v[bb]);
      }
    }
  }

  unsigned int opack[4];
#pragma unroll
  for (int bb = 0; bb < 4; ++bb) {
    const h2 ae = acc[0][bb], ao = acc[1][bb];
    const _Float16 me = ae.x > ae.y ? ae.x : ae.y;
    const _Float16 mo = ao.x > ao.y ? ao.x : ao.y;
    opack[bb] = h2u((h2){me, mo});
  }

  __syncthreads();
#pragma unroll
  for (int bb = 0; bb < 4; ++bb)
    lds[s * 256 + og2 * 64 + bq * 4 + bb] = opack[bb];
  __syncthreads();

  if (t < 256) {
    const int op = t >> 6;
    const int bl = t & 63;
    h2 m = u2h(lds[op * 64 + bl]);
#pragma unroll
    for (int ks = 1; ks < 16; ++ks) {
      const h2 v = u2h(lds[ks * 256 + op * 64 + bl]);
      m = __builtin_elementwise_max(m, v);
    }
    opk[(size_t)(og * 4 + op) * BB + bg * 64 + bl] = h2u(m);
  }
}

// ---------------------------------------------------------------------------
// min-plus + fused fc_out epilogue. LDS buffer sized for the LARGEST aliased
// use: W-stage 8*514=4112 dw, reduce 16*256=4096 dw, ep scratch 4*64*18=4608
// dw  ->  4608 dwords (18.4 KB).  (R11 bug: was 4112 -> ep overflowed.)
// q[b][a] += sum_{o in tile} W_out[a][o]*h3[o][b]; bias via og==0 blocks.
// W_out read wave-uniform (36 scalar dwords/wave). q pre-zeroed by memset.
// ---------------------------------------------------------------------------
__global__ __launch_bounds__(1024) void mmplus_min_fcout_kernel(
    const unsigned int* __restrict__ hpk,   // [H/2][B]
    const float* __restrict__ Wf,           // [H][H] f32
    const float* __restrict__ Wo,           // [A][H] f32
    const float* __restrict__ bo,           // [A]
    float* __restrict__ q) {                // [B][A], pre-zeroed
  constexpr int PITCH = 514;
  __shared__ __align__(16) unsigned int lds[4608];  // 18.4 KB, aliased 3x
  const int t    = threadIdx.x;
  const int lane = t & 63;
  const int og2  = lane >> 4;
  const int bq   = lane & 15;
  const int s    = __builtin_amdgcn_readfirstlane(t >> 6);
  const int og   = blockIdx.x;
  const int bg   = blockIdx.y;

  {
    const int o_l = t >> 7;
    const int c   = t & 127;
    const float4* src = (const float4*)(Wf + (size_t)(og * 8 + o_l) * HH);
    unsigned int* dst = &lds[o_l * PITCH];
#pragma unroll
    for (int k = 0; k < 2; ++k) {
      const float4 v = src[c + 128 * k];
      h2 p0 = {(_Float16)v.x, (_Float16)v.y};
      h2 p1 = {(_Float16)v.z, (_Float16)v.w};
      *(uint2*)&dst[(c + 128 * k) * 2] = make_uint2(h2u(p0), h2u(p1));
    }
  }
  __syncthreads();

  const unsigned int* __restrict__ hp =
      hpk + (size_t)(s * 32) * BB + bg * 64 + bq * 4;
  const _Float16 INIT = (_Float16)(65504.f);
  h2 acc[2][4];
#pragma unroll
  for (int j = 0; j < 2; ++j)
#pragma unroll
    for (int bb = 0; bb < 4; ++bb) acc[j][bb] = (h2){INIT, INIT};

#pragma unroll 4
  for (int it = 0; it < 16; ++it) {
    const int p = it * 2;
    const uint4 h0 = *(const uint4*)(hp + (size_t)p * BB);
    const uint4 h1 = *(const uint4*)(hp + (size_t)(p + 1) * BB);
    const h2 h0v[4] = {u2h(h0.x), u2h(h0.y), u2h(h0.z), u2h(h0.w)};
    const h2 h1v[4] = {u2h(h1.x), u2h(h1.y), u2h(h1.z), u2h(h1.w)};
#pragma unroll
    for (int j = 0; j < 2; ++j) {
      const uint2 wj = *(const uint2*)&lds[(og2 * 2 + j) * PITCH + s * 32 + p];
      const h2 wa = u2h(wj.x);
      const h2 wb = u2h(wj.y);
#pragma unroll
      for (int bb = 0; bb < 4; ++bb) {
        acc[j][bb] = __builtin_elementwise_min(acc[j][bb], wa + h0v[bb]);
        acc[j][bb] = __builtin_elementwise_min(acc[j][bb], wb + h1v[bb]);
      }
    }
  }

  unsigned int opack[4];
#pragma unroll
  for (int bb = 0; bb < 4; ++bb) {
    const h2 ae = acc[0][bb], ao = acc[1][bb];
    const _Float16 me = ae.x < ae.y ? ae.x : ae.y;
    const _Float16 mo = ao.x < ao.y ? ao.x : ao.y;
    opack[bb] = h2u((h2){me, mo});
  }

  __syncthreads();  // W reads done; reuse lds as red[16][4][64]
#pragma unroll
  for (int bb = 0; bb < 4; ++bb)
    lds[s * 256 + og2 * 64 + bq * 4 + bb] = opack[bb];
  __syncthreads();

  // final h3 for (P = og*4+op, b = bg*64+bl) in threads t<256
  h2 m = (h2){(_Float16)0.f, (_Float16)0.f};
  if (t < 256) {
    const int op = t >> 6;
    const int bl = t & 63;
    m = u2h(lds[op * 64 + bl]);
#pragma unroll
    for (int ks = 1; ks < 16; ++ks) {
      const h2 v = u2h(lds[ks * 256 + op * 64 + bl]);
      m = __builtin_elementwise_min(m, v);
    }
  }
  __syncthreads();  // lds free again; reuse as ep[4][64][18] = 4608 dwords

  // ---- fused fc_out partial: ep[op][bl][a] = Wo[a][2P]*m.x + Wo[a][2P+1]*m.y
  float* ep = (float*)lds;
  if (t < 256) {
    const int op = t >> 6;           // wave-uniform
    const int bl = t & 63;
    const float mx = (float)m.x, my = (float)m.y;
    const float* __restrict__ wo = Wo + 2 * (og * 4 + op);  // uniform base
    float* dst = &ep[(op * 64 + bl) * 18];
#pragma unroll
    for (int a = 0; a < AA; ++a) {
      dst[a] = fmaf(wo[(size_t)a * HH], mx, wo[(size_t)a * HH + 1] * my);
    }
  }
  __syncthreads();

  if (t < 64) {
    const int b = bg * 64 + t;
#pragma unroll
    for (int a = 0; a < AA; ++a) {
      float v = ep[(0 * 64 + t) * 18 + a] + ep[(1 * 64 + t) * 18 + a] +
                ep[(2 * 64 + t) * 18 + a] + ep[(3 * 64 + t) * 18 + a];
      if (og == 0) v += bo[a];       // exactly one og==0 block per (b,a)
      atomicAdd(q + (size_t)b * AA + a, v);
    }
  }
}

// ---------------------------------------------------------------------------
extern "C" void kernel_launch(void* const* d_in, const int* in_sizes, int n_in,
                              void* d_out, int out_size, void* d_ws, size_t ws_size,
                              hipStream_t stream) {
  const float* x    = (const float*)d_in[0];
  const float* Wi   = (const float*)d_in[1];
  const float* bi   = (const float*)d_in[2];
  const float* Wmax = (const float*)d_in[3];
  const float* Wmin = (const float*)d_in[4];
  const float* Wo   = (const float*)d_in[5];
  const float* bo   = (const float*)d_in[6];
  float* q = (float*)d_out;

  char* ws = (char*)d_ws;
  unsigned int* h1pk = (unsigned int*)ws;  ws += (size_t)(HH / 2) * BB * 4;  // 512 KB
  unsigned int* h2pk = (unsigned int*)ws;

  hipMemsetAsync(q, 0, (size_t)BB * AA * sizeof(float), stream);  // 18 KB
  fc_in_kernel<<<dim3(HH / 16, BB / 64), 1024, 0, stream>>>(x, Wi, bi, h1pk);
  mmplus_max_kernel<<<dim3(HH / 8, BB / 64), 1024, 0, stream>>>(h1pk, Wmax, h2pk);
  mmplus_min_fcout_kernel<<<dim3(HH / 8, BB / 64), 1024, 0, stream>>>(
      h2pk, Wmin, Wo, bo, q);
}

// Round 13
// 106.867 us; speedup vs baseline: 1.9573x; 1.9573x over previous
//
#include <hip/hip_runtime.h>
#include <math.h>

#define BB   256   // batch
#define OBS  256
#define HH   1024
#define AA   18

// clang-native packed f16: + -> v_pk_add_f16, elementwise_max -> v_pk_max_f16
typedef _Float16 h2 __attribute__((ext_vector_type(2)));

static __device__ __forceinline__ h2 u2h(unsigned int u) {
  return __builtin_bit_cast(h2, u);
}
static __device__ __forceinline__ unsigned int h2u(h2 v) {
  return __builtin_bit_cast(unsigned int, v);
}

// ---------------------------------------------------------------------------
// fc_in: h1pk[o/2][b] = pack_f16( x@W_in^T + b_in ) for o-pair
// grid (H/16, B/64), block 1024 = 8 k-splits x 2 o-octets. lane = b.
// x and W_in tiles staged in LDS (best-measured R10 structure).
// ---------------------------------------------------------------------------
__global__ __launch_bounds__(1024) void fc_in_kernel(
    const float* __restrict__ x, const float* __restrict__ Wi,
    const float* __restrict__ bi, unsigned int* __restrict__ h1pk) {
  __shared__ float xs[64][OBS + 1];    // 65.8 KB
  __shared__ float ws_[16][260];       // 16.6 KB
  __shared__ float red[8][16][64];     // 32 KB
  const int t    = threadIdx.x;
  const int lane = t & 63;
  const int wv   = __builtin_amdgcn_readfirstlane(t >> 6);
  const int oq   = wv & 1;
  const int s    = wv >> 1;        // k-split: 32 k each
  const int og   = blockIdx.x;
  const int bg   = blockIdx.y;
  const int k0   = s * 32;

  {
    const int row = t >> 4;          // 0..63
    const int c4  = t & 15;          // 0..15
    const float4* src = (const float4*)(x + (size_t)(bg * 64 + row) * OBS);
#pragma unroll
    for (int k = 0; k < 4; ++k) {
      const float4 v = src[c4 + 16 * k];
      const int col = (c4 + 16 * k) * 4;
      xs[row][col]     = v.x;
      xs[row][col + 1] = v.y;
      xs[row][col + 2] = v.z;
      xs[row][col + 3] = v.w;
    }
  }
  {
    const int row = wv;              // 0..15
    const int c   = lane;            // 0..63
    const float4 v =
        ((const float4*)(Wi + (size_t)(og * 16 + row) * OBS))[c];
    const int col = c * 4;
    ws_[row][col]     = v.x;
    ws_[row][col + 1] = v.y;
    ws_[row][col + 2] = v.z;
    ws_[row][col + 3] = v.w;
  }
  __syncthreads();

  const int ob = oq * 8;
  float acc[8] = {0, 0, 0, 0, 0, 0, 0, 0};

#pragma unroll
  for (int k = 0; k < 32; k += 4) {
    const int kk = k0 + k;
    const float x0 = xs[lane][kk];
    const float x1 = xs[lane][kk + 1];
    const float x2 = xs[lane][kk + 2];
    const float x3 = xs[lane][kk + 3];
#pragma unroll
    for (int j = 0; j < 8; ++j) {
      const float4 w4 = *(const float4*)&ws_[ob + j][kk];
      acc[j] = fmaf(x0, w4.x, acc[j]);
      acc[j] = fmaf(x1, w4.y, acc[j]);
      acc[j] = fmaf(x2, w4.z, acc[j]);
      acc[j] = fmaf(x3, w4.w, acc[j]);
    }
  }

#pragma unroll
  for (int j = 0; j < 8; ++j) red[s][ob + j][lane] = acc[j];
  __syncthreads();

  if (t < 512) {
    const int op = t >> 6;
    const int bl = t & 63;
    float s0 = 0.f, s1 = 0.f;
#pragma unroll
    for (int ks = 0; ks < 8; ++ks) {
      s0 += red[ks][2 * op][bl];
      s1 += red[ks][2 * op + 1][bl];
    }
    s0 += bi[og * 16 + 2 * op];
    s1 += bi[og * 16 + 2 * op + 1];
    h2 p = {(_Float16)s0, (_Float16)s1};
    h1pk[(size_t)(og * 8 + op) * BB + bg * 64 + bl] = h2u(p);
  }
}

// ---------------------------------------------------------------------------
// mmplus (R8/R10 config — best measured): out[o][b] = OP_i( W[o][i] + h[i][b] )
// grid (H/8, B/64) = 512 blocks, block 1024 = 16 i-splits (64 i each).
// W f32 -> pk f16 into LDS in-flight (pitch 514, conflict-free b64 reads).
// Thread tile 2o x 4b. h coalesced dwordx4.
// ---------------------------------------------------------------------------
template <bool IS_MAX>
__global__ __launch_bounds__(1024) void mmplus_kernel(
    const unsigned int* __restrict__ hpk,   // [H/2][B] dwords (i-pair, b)
    const float* __restrict__ Wf,           // [H][H] f32 (o, i)
    unsigned int* __restrict__ opk) {       // [H/2][B]
  constexpr int PITCH = 514;
  __shared__ __align__(16) unsigned int lds[8 * PITCH];  // 16.4 KB; red aliases
  const int t    = threadIdx.x;
  const int lane = t & 63;
  const int og2  = lane >> 4;      // o-pair group 0..3
  const int bq   = lane & 15;      // b-quad 0..15
  const int s    = __builtin_amdgcn_readfirstlane(t >> 6);  // i-split 0..15
  const int og   = blockIdx.x;     // 0..127, 8 o each
  const int bg   = blockIdx.y;

  {
    const int o_l = t >> 7;        // 0..7
    const int c   = t & 127;
    const float4* src = (const float4*)(Wf + (size_t)(og * 8 + o_l) * HH);
    unsigned int* dst = &lds[o_l * PITCH];
#pragma unroll
    for (int k = 0; k < 2; ++k) {
      const float4 v = src[c + 128 * k];
      h2 p0 = {(_Float16)v.x, (_Float16)v.y};
      h2 p1 = {(_Float16)v.z, (_Float16)v.w};
      *(uint2*)&dst[(c + 128 * k) * 2] = make_uint2(h2u(p0), h2u(p1));
    }
  }
  __syncthreads();

  const unsigned int* __restrict__ hp =
      hpk + (size_t)(s * 32) * BB + bg * 64 + bq * 4;
  const _Float16 INIT = (_Float16)(IS_MAX ? -65504.f : 65504.f);
  h2 acc[2][4];
#pragma unroll
  for (int j = 0; j < 2; ++j)
#pragma unroll
    for (int bb = 0; bb < 4; ++bb) acc[j][bb] = (h2){INIT, INIT};

#pragma unroll 4
  for (int it = 0; it < 16; ++it) {
    const int p = it * 2;
    const uint4 h0 = *(const uint4*)(hp + (size_t)p * BB);
    const uint4 h1 = *(const uint4*)(hp + (size_t)(p + 1) * BB);
    const h2 h0v[4] = {u2h(h0.x), u2h(h0.y), u2h(h0.z), u2h(h0.w)};
    const h2 h1v[4] = {u2h(h1.x), u2h(h1.y), u2h(h1.z), u2h(h1.w)};
#pragma unroll
    for (int j = 0; j < 2; ++j) {
      const uint2 wj = *(const uint2*)&lds[(og2 * 2 + j) * PITCH + s * 32 + p];
      const h2 wa = u2h(wj.x);
      const h2 wb = u2h(wj.y);
#pragma unroll
      for (int bb = 0; bb < 4; ++bb) {
        if (IS_MAX) {
          acc[j][bb] = __builtin_elementwise_max(acc[j][bb], wa + h0v[bb]);
          acc[j][bb] = __builtin_elementwise_max(acc[j][bb], wb + h1v[bb]);
        } else {
          acc[j][bb] = __builtin_elementwise_min(acc[j][bb], wa + h0v[bb]);
          acc[j][bb] = __builtin_elementwise_min(acc[j][bb], wb + h1v[bb]);
        }
      }
    }
  }

  unsigned int opack[4];
#pragma unroll
  for (int bb = 0; bb < 4; ++bb) {
    const h2 ae = acc[0][bb], ao = acc[1][bb];
    const _Float16 me = IS_MAX ? (ae.x > ae.y ? ae.x : ae.y)
                               : (ae.x < ae.y ? ae.x : ae.y);
    const _Float16 mo = IS_MAX ? (ao.x > ao.y ? ao.x : ao.y)
                               : (ao.x < ao.y ? ao.x : ao.y);
    opack[bb] = h2u((h2){me, mo});
  }

  __syncthreads();  // W reads done; reuse lds[] as red[16][4][64] (16 KB)
#pragma unroll
  for (int bb = 0; bb < 4; ++bb)
    lds[s * 256 + og2 * 64 + bq * 4 + bb] = opack[bb];
  __syncthreads();

  if (t < 256) {
    const int op = t >> 6;   // o-pair 0..3
    const int bl = t & 63;
    h2 m = u2h(lds[op * 64 + bl]);
#pragma unroll
    for (int ks = 1; ks < 16; ++ks) {
      const h2 v = u2h(lds[ks * 256 + op * 64 + bl]);
      m = IS_MAX ? __builtin_elementwise_max(m, v)
                 : __builtin_elementwise_min(m, v);
    }
    opk[(size_t)(og * 4 + op) * BB + bg * 64 + bl] = h2u(m);
  }
}

// ---------------------------------------------------------------------------
// fc_out: q[b][a] = bo[a] + dot(h3[:,b], W_out[a,:])
// grid (A, B/64), block 1024 = 16 k-splits x 64 b. No atomics (R12 lesson:
// many-contender global atomics on a tiny output cost ~100 µs).
// ---------------------------------------------------------------------------
__global__ __launch_bounds__(1024) void fc_out_kernel(
    const unsigned int* __restrict__ h3pk, const float* __restrict__ Wo,
    const float* __restrict__ bo, float* __restrict__ q) {
  __shared__ float red[16][64];
  const int a  = blockIdx.x;
  const int bg = blockIdx.y;
  const int t  = threadIdx.x;
  const int bl = t & 63;
  const int ks = __builtin_amdgcn_readfirstlane(t >> 6);  // 0..15

  const unsigned int* __restrict__ hp =
      h3pk + (size_t)(ks * 32) * BB + bg * 64 + bl;
  const float* __restrict__ w = Wo + (size_t)a * HH + ks * 64;

  float acc = 0.f;
#pragma unroll 8
  for (int d = 0; d < 32; ++d) {
    const h2 hv = u2h(hp[(size_t)d * BB]);
    acc = fmaf((float)hv.x, w[2 * d], acc);
    acc = fmaf((float)hv.y, w[2 * d + 1], acc);
  }
  red[ks][bl] = acc;
  __syncthreads();

  if (t < 64) {
    float m = bo[a];
#pragma unroll
    for (int ks2 = 0; ks2 < 16; ++ks2) m += red[ks2][t];
    q[(size_t)(bg * 64 + t) * AA + a] = m;
  }
}

// ---------------------------------------------------------------------------
extern "C" void kernel_launch(void* const* d_in, const int* in_sizes, int n_in,
                              void* d_out, int out_size, void* d_ws, size_t ws_size,
                              hipStream_t stream) {
  const float* x    = (const float*)d_in[0];
  const float* Wi   = (const float*)d_in[1];
  const float* bi   = (const float*)d_in[2];
  const float* Wmax = (const float*)d_in[3];
  const float* Wmin = (const float*)d_in[4];
  const float* Wo   = (const float*)d_in[5];
  const float* bo   = (const float*)d_in[6];
  float* q = (float*)d_out;

  char* ws = (char*)d_ws;
  unsigned int* h1pk = (unsigned int*)ws;  ws += (size_t)(HH / 2) * BB * 4;  // 512 KB
  unsigned int* h2pk = (unsigned int*)ws;  ws += (size_t)(HH / 2) * BB * 4;
  unsigned int* h3pk = (unsigned int*)ws;

  fc_in_kernel<<<dim3(HH / 16, BB / 64), 1024, 0, stream>>>(x, Wi, bi, h1pk);
  mmplus_kernel<true ><<<dim3(HH / 8, BB / 64), 1024, 0, stream>>>(h1pk, Wmax, h2pk);
  mmplus_kernel<false><<<dim3(HH / 8, BB / 64), 1024, 0, stream>>>(h2pk, Wmin, h3pk);
  fc_out_kernel<<<dim3(AA, BB / 64), 1024, 0, stream>>>(h3pk, Wo, bo, q);
}